// Round 1
// baseline (1329.883 us; speedup 1.0000x reference)
//
#include <hip/hip_runtime.h>

#define BATCH 32
#define CIN   512
#define H     112
#define W     112
#define RC    32
#define CPG   16
#define HO    56
#define WO    56
#define S     3136      // HO*WO
#define TY    4         // output rows per conv block
#define NTILE 14        // HO/TY
#define SC    16        // s-chunks for mat kernel
#define CH    196       // S/SC
#define CHP   204       // padded LDS row stride (mult of 4; 2*CHP%32==24 -> 4-way max)

// workspace layout (float offsets)
#define WS_THETA 0
#define WS_PHI   (RC*BATCH*S)             // 3211264
#define WS_GAP   (2*RC*BATCH*S)           // 6422528
#define WS_MAT   (WS_GAP + BATCH*CIN)     // 6438912  (size BATCH*SC*RC*RC)

// Kernel 1: grouped 3x3 stride-2 convs (theta & phi share x loads) + GAP partials.
__global__ __launch_bounds__(256)
void conv_gap_kernel(const float* __restrict__ x,
                     const float* __restrict__ thw, const float* __restrict__ thb,
                     const float* __restrict__ phw, const float* __restrict__ phb,
                     float* __restrict__ theta_out, float* __restrict__ phi_out,
                     float* __restrict__ gapsum)
{
    const int ty  = blockIdx.x;   // 0..13 row tile
    const int g   = blockIdx.y;   // group / output channel
    const int b   = blockIdx.z;
    const int tid = threadIdx.x;

    __shared__ float wth[CPG*9], wph[CPG*9];
    if (tid < CPG*9) {
        wth[tid] = thw[g*(CPG*9) + tid];
        wph[tid] = phw[g*(CPG*9) + tid];
    }
    __syncthreads();

    const float* xg = x + (size_t)(b*CIN + g*CPG) * (H*W);

    // ---- conv part: 224 threads = 56 cols x 4 rows ----
    if (tid < WO*TY) {
        const int ox = tid % WO;
        const int oy = ty*TY + tid / WO;
        float at = thb[g];
        float ap = phb[g];
        const int iy0 = 2*oy - 1;
        const int ix0 = 2*ox - 1;
        for (int i = 0; i < CPG; ++i) {
            const float* xc = xg + i*(H*W);
            #pragma unroll
            for (int ky = 0; ky < 3; ++ky) {
                const int iy = iy0 + ky;
                if ((unsigned)iy < (unsigned)H) {
                    const float* row = xc + iy*W;
                    #pragma unroll
                    for (int kx = 0; kx < 3; ++kx) {
                        const int ix = ix0 + kx;
                        if ((unsigned)ix < (unsigned)W) {
                            const float v = row[ix];
                            at = fmaf(v, wth[i*9 + ky*3 + kx], at);
                            ap = fmaf(v, wph[i*9 + ky*3 + kx], ap);
                        }
                    }
                }
            }
        }
        const size_t o = (size_t)(b*RC + g)*S + oy*WO + ox;
        theta_out[o] = at;
        phi_out[o]  = ap;
    }

    // ---- GAP part: this block owns input rows [8*ty, 8*ty+8), 16 channels ----
    {
        const int c = tid >> 4;   // 0..15 channel within group
        const int j = tid & 15;
        const float* xc = xg + c*(H*W) + (8*ty)*W;
        float ssum = 0.f;
        for (int e = j; e < 8*W; e += 16) ssum += xc[e];
        #pragma unroll
        for (int off = 8; off; off >>= 1) ssum += __shfl_down(ssum, off, 16);
        if (j == 0) atomicAdd(&gapsum[b*CIN + g*CPG + c], ssum);
    }
}

// Kernel 2: partial Gram matrices mat[b,c,d] over s-chunks (fp32, 2x2 reg tile).
__global__ __launch_bounds__(256)
void mat_kernel(const float* __restrict__ theta, const float* __restrict__ phi,
                float* __restrict__ matpart)
{
    const int sc  = blockIdx.x;   // 0..15
    const int b   = blockIdx.y;
    const int tid = threadIdx.x;

    __shared__ float th_s[RC*CHP];
    __shared__ float ph_s[RC*CHP];

    const size_t gbase = (size_t)b*RC*S + (size_t)sc*CH;
    for (int idx = tid; idx < RC*CH; idx += 256) {
        const int c = idx / CH;
        const int s = idx - c*CH;
        th_s[c*CHP + s] = theta[gbase + (size_t)c*S + s];
        ph_s[c*CHP + s] = phi[gbase + (size_t)c*S + s];
    }
    __syncthreads();

    const int cpair = tid >> 4;
    const int dpair = tid & 15;
    const int c0 = 2*cpair, c1 = c0 + 1;
    const int d0 = 2*dpair, d1 = d0 + 1;

    float a00 = 0.f, a01 = 0.f, a10 = 0.f, a11 = 0.f;
    for (int s4 = 0; s4 < CH; s4 += 4) {
        const float4 ta = *(const float4*)(th_s + c0*CHP + s4);
        const float4 tb = *(const float4*)(th_s + c1*CHP + s4);
        const float4 pa = *(const float4*)(ph_s + d0*CHP + s4);
        const float4 pb = *(const float4*)(ph_s + d1*CHP + s4);
        a00 += ta.x*pa.x + ta.y*pa.y + ta.z*pa.z + ta.w*pa.w;
        a01 += ta.x*pb.x + ta.y*pb.y + ta.z*pb.z + ta.w*pb.w;
        a10 += tb.x*pa.x + tb.y*pa.y + tb.z*pa.z + tb.w*pa.w;
        a11 += tb.x*pb.x + tb.y*pb.y + tb.z*pb.z + tb.w*pb.w;
    }
    float* mp = matpart + ((size_t)b*SC + sc)*(RC*RC);
    mp[c0*RC + d0] = a00;
    mp[c0*RC + d1] = a01;
    mp[c1*RC + d0] = a10;
    mp[c1*RC + d1] = a11;
}

// Kernel 3: reduce partials, g = fc(gap), softmax rows, out = softmax(mat) @ g.
__global__ __launch_bounds__(64)
void final_kernel(const float* __restrict__ matpart, const float* __restrict__ gapsum,
                  const float* __restrict__ fcw, const float* __restrict__ fcb,
                  float* __restrict__ out)
{
    const int b   = blockIdx.x;
    const int tid = threadIdx.x;
    __shared__ float m_s[RC*33];   // padded rows to avoid bank conflicts
    __shared__ float g_s[RC];

    for (int idx = tid; idx < RC*RC; idx += 64) {
        float s = 0.f;
        const float* mp = matpart + (size_t)b*SC*RC*RC + idx;
        #pragma unroll
        for (int sc = 0; sc < SC; ++sc) s += mp[sc*RC*RC];
        m_s[(idx >> 5)*33 + (idx & 31)] = s;
    }
    if (tid < RC) {
        const float* gp = gapsum + b*CIN + tid*CPG;
        const float* wp = fcw + tid*CPG;
        float acc = 0.f;
        for (int i = 0; i < CPG; ++i) acc += gp[i]*wp[i];
        g_s[tid] = fcb[tid] + acc * (1.0f/(float)(H*W));
    }
    __syncthreads();
    if (tid < RC) {
        const float* row = m_s + tid*33;
        float m = -1e30f;
        for (int d = 0; d < RC; ++d) m = fmaxf(m, row[d]);
        float se = 0.f, num = 0.f;
        for (int d = 0; d < RC; ++d) {
            const float e = expf(row[d] - m);
            se  += e;
            num += e * g_s[d];
        }
        out[b*RC + tid] = num / se;
    }
}

extern "C" void kernel_launch(void* const* d_in, const int* in_sizes, int n_in,
                              void* d_out, int out_size, void* d_ws, size_t ws_size,
                              hipStream_t stream)
{
    const float* x   = (const float*)d_in[0];
    const float* thw = (const float*)d_in[1];
    const float* thb = (const float*)d_in[2];
    const float* phw = (const float*)d_in[3];
    const float* phb = (const float*)d_in[4];
    const float* fcw = (const float*)d_in[5];
    const float* fcb = (const float*)d_in[6];
    float* out = (float*)d_out;
    float* ws  = (float*)d_ws;

    float* theta = ws + WS_THETA;
    float* phi   = ws + WS_PHI;
    float* gap   = ws + WS_GAP;
    float* mat   = ws + WS_MAT;

    hipMemsetAsync(gap, 0, BATCH*CIN*sizeof(float), stream);
    conv_gap_kernel<<<dim3(NTILE, RC, BATCH), 256, 0, stream>>>(
        x, thw, thb, phw, phb, theta, phi, gap);
    mat_kernel<<<dim3(SC, BATCH), 256, 0, stream>>>(theta, phi, mat);
    final_kernel<<<BATCH, 64, 0, stream>>>(mat, gap, fcw, fcb, out);
}

// Round 2
// 1133.591 us; speedup vs baseline: 1.1732x; 1.1732x over previous
//
#include <hip/hip_runtime.h>

#define BATCH 32
#define CIN   512
#define HH    112
#define WW    112
#define RC    32
#define CPG   16
#define HO    56
#define WO    56
#define TY    4
#define NTILE 14            // HO/TY
#define SPT   (TY*WO)       // 224 spatial outputs per block
#define XROWS 9             // staged input rows (2*TY+1)
#define XW    120           // staged row stride: 4 left-pad + 112 + 4 tail
#define TSP   228           // theta/phi tile row stride (224+4)
#define HW    (HH*WW)       // 12544

// ws layout (float offsets)
#define WS_MAT 0
#define WS_GAP (BATCH*NTILE*RC*RC)   // 458752 floats for matpart, then 14336 for gpart

__device__ __forceinline__ float4 ldx(const float* p, bool pred) {
    float4 v = make_float4(0.f, 0.f, 0.f, 0.f);
    if (pred) v = *(const float4*)p;
    return v;
}

// One block = one (spatial row-tile, batch). Computes grouped theta/phi convs for
// ALL 32 groups from a single staged read of x, the 32x32 Gram partial for its
// spatial tile, and the fc(GAP) partial. x is read from HBM exactly once (+halo).
__global__ __launch_bounds__(256, 2)
void conv_gram_kernel(const float* __restrict__ x,
                      const float* __restrict__ thw, const float* __restrict__ thb,
                      const float* __restrict__ phw, const float* __restrict__ phb,
                      const float* __restrict__ fcw,
                      float* __restrict__ matpart, float* __restrict__ gpart)
{
    const int t   = blockIdx.x;   // 0..13
    const int b   = blockIdx.y;
    const int tid = threadIdx.x;

    __shared__ __align__(16) float xs[2][XROWS*XW];
    __shared__ __align__(16) float th_s[RC*TSP];
    __shared__ __align__(16) float ph_s[RC*TSP];
    __shared__ float g_red[4*RC];

    // zero the left/right pad columns of both staging buffers (once)
    for (int r = tid; r < XROWS; r += 256) {
        #pragma unroll
        for (int k = 0; k < 4; ++k) {
            xs[0][r*XW + k] = 0.f;       xs[1][r*XW + k] = 0.f;
            xs[0][r*XW + 116 + k] = 0.f; xs[1][r*XW + 116 + k] = 0.f;
        }
    }

    // ---- staging geometry: 9 contiguous input rows = 1008 floats = 252 float4 ----
    const bool sact = tid < 252;
    const int  srow = (4*tid) / WW;          // 0..8 (local row)
    const int  scol = (4*tid) % WW;
    const bool oobz = (t == 0) && (srow == 0);   // input row -1 -> stage zeros
    const bool ldp  = sact && !oobz;
    const bool gapv = sact && (srow >= 1);       // rows 1..8 = GAP rows [8t,8t+8)
    const float* xbase = x + (size_t)b*CIN*HW + (long)(8*t - 1 + srow)*WW + scol;
    const int  sdst = srow*XW + 4 + scol;        // 16B aligned

    // ---- conv geometry ----
    const bool cact = tid < SPT;
    const int  ry   = tid / WO;                  // 0..3
    const int  ox   = tid - ry*WO;               // 0..55
    const int  cbase = (2*ry)*XW + 3 + 2*ox;     // local addr of (iy0, ix0) with pads

    // preamble: channel 0 staged into xs[0]; prefetch ch1, ch2
    float4 v0 = ldx(xbase, ldp);
    if (sact) *(float4*)(&xs[0][sdst]) = v0;
    float gcur = gapv ? (v0.x + v0.y + v0.z + v0.w) * fcw[0] : 0.f;
    float4 va = ldx(xbase + (size_t)1*HW, ldp);
    float4 vb = ldx(xbase + (size_t)2*HW, ldp);

    for (int g = 0; g < RC; ++g) {
        float tacc = thb[g];
        float pacc = phb[g];
        #pragma unroll 4
        for (int i = 0; i < CPG; ++i) {
            const int ch = g*CPG + i;
            // prefetch depth-2: issue load for ch+3 now
            float4 vn = make_float4(0.f, 0.f, 0.f, 0.f);
            if (ch + 3 < CIN) vn = ldx(xbase + (size_t)(ch + 3)*HW, ldp);

            __syncthreads();   // xs[ch&1] fully staged; prev buffer reads done

            if (cact) {
                const float* xr = &xs[ch & 1][cbase];
                const float* wt = thw + ch*9;      // uniform -> scalar loads
                const float* wp = phw + ch*9;
                const float a0 = xr[0],      a1 = xr[1],      a2 = xr[2];
                const float b0 = xr[XW],     b1 = xr[XW+1],   b2 = xr[XW+2];
                const float c0 = xr[2*XW],   c1 = xr[2*XW+1], c2 = xr[2*XW+2];
                tacc = fmaf(a0, wt[0], tacc); pacc = fmaf(a0, wp[0], pacc);
                tacc = fmaf(a1, wt[1], tacc); pacc = fmaf(a1, wp[1], pacc);
                tacc = fmaf(a2, wt[2], tacc); pacc = fmaf(a2, wp[2], pacc);
                tacc = fmaf(b0, wt[3], tacc); pacc = fmaf(b0, wp[3], pacc);
                tacc = fmaf(b1, wt[4], tacc); pacc = fmaf(b1, wp[4], pacc);
                tacc = fmaf(b2, wt[5], tacc); pacc = fmaf(b2, wp[5], pacc);
                tacc = fmaf(c0, wt[6], tacc); pacc = fmaf(c0, wp[6], pacc);
                tacc = fmaf(c1, wt[7], tacc); pacc = fmaf(c1, wp[7], pacc);
                tacc = fmaf(c2, wt[8], tacc); pacc = fmaf(c2, wp[8], pacc);
            }

            if (i == CPG - 1) {
                // group g done: publish tiles + reduce fc(GAP) partial for this group
                if (cact) { th_s[g*TSP + tid] = tacc; ph_s[g*TSP + tid] = pacc; }
                float r = gcur;
                #pragma unroll
                for (int off = 32; off; off >>= 1) r += __shfl_down(r, off);
                if ((tid & 63) == 0) g_red[(tid >> 6)*RC + g] = r;
                gcur = 0.f;
            }

            if (ch + 1 < CIN) {
                // stage ch+1 (loaded 2 iters ago); fold its GAP contribution
                if (sact) *(float4*)(&xs[(ch + 1) & 1][sdst]) = va;
                if (gapv) gcur = fmaf(va.x + va.y + va.z + va.w, fcw[ch + 1], gcur);
                va = vb; vb = vn;
            }
        }
    }

    __syncthreads();   // tiles + g_red complete

    // ---- Gram partial: thread (c = tid>>3, dq = tid&7) handles d in {dq, dq+8, dq+16, dq+24}
    {
        const int c  = tid >> 3;
        const int dq = tid & 7;
        const float* tr = th_s + c*TSP;
        const float* p0 = ph_s + dq*TSP;
        float a0 = 0.f, a1 = 0.f, a2 = 0.f, a3 = 0.f;
        for (int s = 0; s < SPT; s += 4) {
            const float4 tv = *(const float4*)(tr + s);
            const float4 q0 = *(const float4*)(p0 + s);
            const float4 q1 = *(const float4*)(p0 + 8*TSP + s);
            const float4 q2 = *(const float4*)(p0 + 16*TSP + s);
            const float4 q3 = *(const float4*)(p0 + 24*TSP + s);
            a0 += tv.x*q0.x + tv.y*q0.y + tv.z*q0.z + tv.w*q0.w;
            a1 += tv.x*q1.x + tv.y*q1.y + tv.z*q1.z + tv.w*q1.w;
            a2 += tv.x*q2.x + tv.y*q2.y + tv.z*q2.z + tv.w*q2.w;
            a3 += tv.x*q3.x + tv.y*q3.y + tv.z*q3.z + tv.w*q3.w;
        }
        float* mp = matpart + ((size_t)b*NTILE + t)*(RC*RC) + c*RC + dq;
        mp[0]  = a0;
        mp[8]  = a1;
        mp[16] = a2;
        mp[24] = a3;
    }

    if (tid < RC) {
        const float s = g_red[tid] + g_red[RC + tid] + g_red[2*RC + tid] + g_red[3*RC + tid];
        gpart[((size_t)b*NTILE + t)*RC + tid] = s;
    }
}

// Reduce the 14 spatial partials, build g, softmax rows, emit [B,RC,1,1].
__global__ __launch_bounds__(256)
void final_kernel(const float* __restrict__ matpart, const float* __restrict__ gpart,
                  const float* __restrict__ fcb, float* __restrict__ out)
{
    const int b   = blockIdx.x;
    const int tid = threadIdx.x;
    __shared__ float m_s[RC*33];
    __shared__ float g_s[RC];

    for (int idx = tid; idx < RC*RC; idx += 256) {
        float s = 0.f;
        const float* mp = matpart + (size_t)b*NTILE*RC*RC + idx;
        #pragma unroll
        for (int tt = 0; tt < NTILE; ++tt) s += mp[tt*RC*RC];
        m_s[(idx >> 5)*33 + (idx & 31)] = s;
    }
    if (tid < RC) {
        float s = 0.f;
        const float* gp = gpart + (size_t)b*NTILE*RC + tid;
        #pragma unroll
        for (int tt = 0; tt < NTILE; ++tt) s += gp[tt*RC];
        g_s[tid] = fcb[tid] + s * (1.0f/(float)HW);
    }
    __syncthreads();
    if (tid < RC) {
        const float* row = m_s + tid*33;
        float m = -1e30f;
        for (int d = 0; d < RC; ++d) m = fmaxf(m, row[d]);
        float se = 0.f, num = 0.f;
        for (int d = 0; d < RC; ++d) {
            const float e = expf(row[d] - m);
            se  += e;
            num += e * g_s[d];
        }
        out[b*RC + tid] = num / se;
    }
}

extern "C" void kernel_launch(void* const* d_in, const int* in_sizes, int n_in,
                              void* d_out, int out_size, void* d_ws, size_t ws_size,
                              hipStream_t stream)
{
    const float* x   = (const float*)d_in[0];
    const float* thw = (const float*)d_in[1];
    const float* thb = (const float*)d_in[2];
    const float* phw = (const float*)d_in[3];
    const float* phb = (const float*)d_in[4];
    const float* fcw = (const float*)d_in[5];
    const float* fcb = (const float*)d_in[6];
    float* out = (float*)d_out;
    float* ws  = (float*)d_ws;

    float* matpart = ws + WS_MAT;
    float* gpart   = ws + WS_GAP;

    conv_gram_kernel<<<dim3(NTILE, BATCH), 256, 0, stream>>>(
        x, thw, thb, phw, phb, fcw, matpart, gpart);
    final_kernel<<<BATCH, 256, 0, stream>>>(matpart, gpart, fcb, out);
}